// Round 4
// baseline (28.540 us; speedup 1.0000x reference)
//
#include <hip/hip_runtime.h>

// Problem constants (fixed by reference setup_inputs):
//   B=64, IN=512, OUT=512, K=2, KK=4, T=IN*OUT=262144, TPO=T/OUT=512
constexpr int B    = 64;
constexpr int IN   = 512;
constexpr int OUT  = 512;
constexpr int T    = IN * OUT;
constexpr int TPO  = T / OUT;     // 512 tables per output feature
constexpr int TPW  = TPO / 4;     // 128 tables per wave-group
constexpr int BH   = 32;          // batch rows staged per block
constexpr int PAD  = BH + 1;      // 33: LDS row stride (conflict-free)

// Transform lut_weights[t][4] -> bilinear coefficients (A,B,C,D):
// per_table = A + B*x0 + C*x1 + D*x0*x1
__global__ void lut_coeff_kernel(const float4* __restrict__ lut,
                                 float4* __restrict__ coeff) {
    int t = blockIdx.x * blockDim.x + threadIdx.x;
    if (t < T) {
        float4 w = lut[t];
        float4 c;
        c.x = ( w.x + w.y + w.z + w.w) * 0.25f;   // A
        c.y = (-w.x + w.y - w.z + w.w) * 0.25f;   // B (x0)
        c.z = (-w.x - w.y + w.z + w.w) * 0.25f;   // C (x1)
        c.w = ( w.x - w.y - w.z + w.w) * 0.25f;   // D (x0*x1)
        coeff[t] = c;
    }
}

// One block = 512 threads = 8 waves; handles 2 output features for a
// 32-row batch half. grid = (OUT/2, B/32) = (256, 2) -> 512 blocks,
// 2 blocks/CU (LDS 68.6 KB) = 4 waves/SIMD.
// Wave w: feature o = bx*2 + (w>>2), table slice (w&3)*128..+128.
// Per iteration a wave covers 2 adjacent tables (p = lane>>5) x 32
// batches (bb = lane&31); parity halves combined via shfl_xor(32).
template <bool USE_COEFF>
__global__ __launch_bounds__(512, 4)
void lut_main_kernel(const float* __restrict__ input,   // [B][IN]
                     const int*   __restrict__ mask,    // [T*2]
                     const float4* __restrict__ tab,    // coeff or raw lut
                     const float* __restrict__ bias,    // [OUT]
                     float* __restrict__ out) {         // [B][OUT]
    __shared__ float xs[IN * PAD];    // 512*33*4 = 67.6 KB
    __shared__ float red[8 * BH];     // 1 KB

    const int tid = threadIdx.x;
    const int b0  = blockIdx.y * BH;

    // Stage transposed: xs[i*33 + b] = input[(b0+b)*IN + i].
    // Coalesced global reads; LDS writes hit banks (i+b)%32 -> free.
    for (int f = tid; f < BH * IN; f += 512) {
        int b = f >> 9;        // f / IN
        int i = f & (IN - 1);  // f % IN
        xs[i * PAD + b] = input[(b0 + b) * IN + i];
    }
    __syncthreads();

    const int lane = tid & 63;
    const int bb   = lane & 31;   // batch within half
    const int p    = lane >> 5;   // table parity
    const int w    = tid >> 6;    // wave 0..7
    const int o    = blockIdx.x * 2 + (w >> 2);
    const int t0   = o * TPO + (w & 3) * TPW;

    const int2* m2 = reinterpret_cast<const int2*>(mask);

    float acc = 0.0f;
#pragma unroll 8
    for (int j = 0; j < TPW / 2; ++j) {        // 64 iterations
        const int    t = t0 + 2 * j + p;
        const int2   m = m2[t];    // 2 addrs/wave, one 16B segment
        const float4 c = tab[t];   // 2 addrs/wave, one 32B segment
        float A, Bc, Cc, Dd;
        if constexpr (USE_COEFF) {
            A = c.x; Bc = c.y; Cc = c.z; Dd = c.w;
        } else {
            A  = ( c.x + c.y + c.z + c.w) * 0.25f;
            Bc = (-c.x + c.y - c.z + c.w) * 0.25f;
            Cc = (-c.x - c.y + c.z + c.w) * 0.25f;
            Dd = ( c.x - c.y - c.z + c.w) * 0.25f;
        }
        const float x0 = xs[m.x * PAD + bb];
        const float x1 = xs[m.y * PAD + bb];
        acc += A + Bc * x0 + Cc * x1 + Dd * (x0 * x1);
    }

    // Combine parity halves, then cross-wave reduce in LDS.
    acc += __shfl_xor(acc, 32);
    if (p == 0) red[w * BH + bb] = acc;
    __syncthreads();

    if (tid < 2 * BH) {
        const int f  = tid >> 5;      // feature within block
        const int b  = tid & 31;
        const int rb = f * 4 * BH;
        float s = red[rb + b] + red[rb + BH + b] +
                  red[rb + 2 * BH + b] + red[rb + 3 * BH + b];
        const int oo = blockIdx.x * 2 + f;
        out[(b0 + b) * OUT + oo] = s + bias[oo];
    }
}

extern "C" void kernel_launch(void* const* d_in, const int* in_sizes, int n_in,
                              void* d_out, int out_size, void* d_ws, size_t ws_size,
                              hipStream_t stream) {
    const float*  input = (const float*)d_in[0];
    const int*    mask  = (const int*)d_in[1];
    const float*  lut   = (const float*)d_in[2];
    const float*  bias  = (const float*)d_in[3];
    float*        out   = (float*)d_out;

    const size_t coeff_bytes = (size_t)T * 4 * sizeof(float);  // 4 MB

    dim3 grid(OUT / 2, B / BH), block(512);

    if (ws_size >= coeff_bytes) {
        float4* coeff = (float4*)d_ws;
        lut_coeff_kernel<<<dim3(T / 256), dim3(256), 0, stream>>>(
            (const float4*)lut, coeff);
        lut_main_kernel<true><<<grid, block, 0, stream>>>(
            input, mask, coeff, bias, out);
    } else {
        lut_main_kernel<false><<<grid, block, 0, stream>>>(
            input, mask, (const float4*)lut, bias, out);
    }
}

// Round 5
// 21.853 us; speedup vs baseline: 1.3060x; 1.3060x over previous
//
#include <hip/hip_runtime.h>

// Problem constants (fixed by reference setup_inputs):
//   B=64, IN=512, OUT=512, K=2, KK=4, T=IN*OUT=262144, TPO=T/OUT=512
constexpr int B    = 64;
constexpr int IN   = 512;
constexpr int OUT  = 512;
constexpr int T    = IN * OUT;
constexpr int TPO  = T / OUT;     // 512 tables per output feature
constexpr int TPW  = TPO / 4;     // 128 tables per wave (4 waves/feature)
constexpr int PAD  = B + 1;       // 65: LDS row stride (conflict-free)

// Single kernel. One block = 512 threads = 8 waves, 2 output features.
// lane = batch (64 = full wave); waves 0-3 -> feature 0, 4-7 -> feature 1.
// Per-table mask/lut loads are wave-uniform: wave id is pinned uniform via
// readfirstlane so the compiler emits scalar s_load_dwordx2/x4 (constant
// cache), keeping the vector-memory pipe free for the LDS gathers.
// Bilinear collapse: per_table = A + B*x0 + C*x1 + D*x0*x1 with
// (A,B,C,D) = (+/- sums of lut[t][0..3]) * 0.25, done inline on VALU.
__global__ __launch_bounds__(512, 1)
void lut_main_kernel(const float* __restrict__ input,   // [B][IN]
                     const int*   __restrict__ mask,    // [T*2]
                     const float4* __restrict__ lut,    // [T][4]
                     const float* __restrict__ bias,    // [OUT]
                     float* __restrict__ out) {         // [B][OUT]
    __shared__ float xs[IN * PAD];    // 130 KB: xs[i*65 + b]
    __shared__ float red[8 * B];      // 2 KB

    const int tid = threadIdx.x;

    // Stage input transposed via float4: in4[f4] covers 4 consecutive i
    // of one batch row b. Global loads fully coalesced (16B/lane).
    const float4* in4 = reinterpret_cast<const float4*>(input);
    for (int f4 = tid; f4 < B * IN / 4; f4 += 512) {
        const float4 v = in4[f4];
        const int f = f4 * 4;
        const int b = f >> 9;         // f / IN
        const int i = f & (IN - 1);   // f % IN
        xs[(i + 0) * PAD + b] = v.x;
        xs[(i + 1) * PAD + b] = v.y;
        xs[(i + 2) * PAD + b] = v.z;
        xs[(i + 3) * PAD + b] = v.w;
    }
    __syncthreads();

    const int lane = tid & 63;                                // batch
    const int w    = __builtin_amdgcn_readfirstlane(tid >> 6); // wave 0..7 (uniform)
    const int o    = blockIdx.x * 2 + (w >> 2);
    const int t0   = o * TPO + (w & 3) * TPW;

    const int2*   m2 = reinterpret_cast<const int2*>(mask) + t0;  // uniform ptr
    const float4* w4 = lut + t0;                                  // uniform ptr

    float acc = 0.0f;
#pragma unroll 8
    for (int j = 0; j < TPW; ++j) {
        const int2   m = m2[j];   // uniform -> s_load_dwordx2
        const float4 c = w4[j];   // uniform -> s_load_dwordx4
        const float A  = ( c.x + c.y + c.z + c.w) * 0.25f;
        const float Bc = (-c.x + c.y - c.z + c.w) * 0.25f;
        const float Cc = (-c.x - c.y + c.z + c.w) * 0.25f;
        const float Dd = ( c.x - c.y - c.z + c.w) * 0.25f;
        const float x0 = xs[m.x * PAD + lane];   // banks (m.x+lane)%32: 2-way, free
        const float x1 = xs[m.y * PAD + lane];
        acc += A + Bc * x0 + Cc * x1 + Dd * (x0 * x1);
    }

    red[w * B + lane] = acc;
    __syncthreads();

    // Waves 0,1 finish features 0,1: sum the 4 wave partials.
    if (w < 2) {
        const int oo = blockIdx.x * 2 + w;
        const int rb = w * 4 * B;
        const float s = red[rb + lane] + red[rb + B + lane] +
                        red[rb + 2 * B + lane] + red[rb + 3 * B + lane];
        out[lane * OUT + oo] = s + bias[oo];
    }
}

extern "C" void kernel_launch(void* const* d_in, const int* in_sizes, int n_in,
                              void* d_out, int out_size, void* d_ws, size_t ws_size,
                              hipStream_t stream) {
    const float*  input = (const float*)d_in[0];
    const int*    mask  = (const int*)d_in[1];
    const float*  lut   = (const float*)d_in[2];
    const float*  bias  = (const float*)d_in[3];
    float*        out   = (float*)d_out;

    dim3 grid(OUT / 2), block(512);
    lut_main_kernel<<<grid, block, 0, stream>>>(
        input, mask, (const float4*)lut, bias, out);
}

// Round 6
// 19.468 us; speedup vs baseline: 1.4660x; 1.1225x over previous
//
#include <hip/hip_runtime.h>

// Problem constants (fixed by reference setup_inputs):
//   B=64, IN=512, OUT=512, K=2, KK=4, T=IN*OUT=262144, TPO=T/OUT=512
constexpr int B    = 64;
constexpr int IN   = 512;
constexpr int OUT  = 512;
constexpr int T    = IN * OUT;
constexpr int TPO  = T / OUT;     // 512 tables per output feature
constexpr int TPW  = TPO / 4;     // 128 tables per wave (4 waves/feature)
constexpr int STR  = 68;          // xs row stride (dwords): [IN][STR]
// Reads xs[i*68 + lane]: banks (4i+lane)%32 -> 2-way for wave64 (free).
// Staged writes ds_write_b128 at xs[i*68 + b4]: consecutive lanes' 16B
// blocks start at banks (4i+b4)%32 -> each 8-lane phase tiles all 32
// banks exactly once (conflict-free).

__device__ __forceinline__ float bcast_f(float v, int j) {
    return __int_as_float(__builtin_amdgcn_readlane(__float_as_int(v), j));
}

// One block = 512 threads = 8 waves, 2 output features; grid = 256.
// lane = batch. Per wave: its 128 tables' mask/lut are fetched with 4
// coalesced vector loads (lane l holds table t0+l and t0+64+l), the
// bilinear transform (A,B,C,D) = (+/- sums)*0.25 is done once per lane,
// and the inner loop broadcasts lane j's registers via v_readlane --
// no per-table memory traffic, no s_load/ds_read lgkmcnt mixing.
__global__ __launch_bounds__(512, 1)
void lut_main_kernel(const float* __restrict__ input,   // [B][IN]
                     const int2*  __restrict__ mask2,   // [T]
                     const float4* __restrict__ lut,    // [T][4]
                     const float* __restrict__ bias,    // [OUT]
                     float* __restrict__ out) {         // [B][OUT]
    __shared__ float xs[IN * STR];    // 139.3 KB
    __shared__ float red[8 * B];      // 2 KB

    const int tid = threadIdx.x;

    // ---- Stage input as xs[i][b] (thread tid owns column i = tid). ----
    // Global: input[(b4+k)*512 + i] -> 256B coalesced per instruction.
    // LDS: one aligned ds_write_b128 per 4 batches (conflict-free).
    {
        const int i = tid;
        for (int b4 = 0; b4 < B; b4 += 4) {
            float a0 = input[(b4 + 0) * IN + i];
            float a1 = input[(b4 + 1) * IN + i];
            float a2 = input[(b4 + 2) * IN + i];
            float a3 = input[(b4 + 3) * IN + i];
            *reinterpret_cast<float4*>(&xs[i * STR + b4]) =
                make_float4(a0, a1, a2, a3);
        }
    }
    __syncthreads();

    const int lane = tid & 63;            // batch
    const int w    = tid >> 6;            // wave 0..7
    const int o    = blockIdx.x * 2 + (w >> 2);
    const int t0   = o * TPO + (w & 3) * TPW;

    // Coalesced per-lane table data: 4 VMEM loads cover 128 tables.
    const int2   m0 = mask2[t0 + lane];
    const int2   m1 = mask2[t0 + 64 + lane];
    const float4 c0 = lut[t0 + lane];
    const float4 c1 = lut[t0 + 64 + lane];

    // Per-lane bilinear transform (amortized 64x vs in-loop).
    float4 d0, d1;
    d0.x = ( c0.x + c0.y + c0.z + c0.w) * 0.25f;
    d0.y = (-c0.x + c0.y - c0.z + c0.w) * 0.25f;
    d0.z = (-c0.x - c0.y + c0.z + c0.w) * 0.25f;
    d0.w = ( c0.x - c0.y - c0.z + c0.w) * 0.25f;
    d1.x = ( c1.x + c1.y + c1.z + c1.w) * 0.25f;
    d1.y = (-c1.x + c1.y - c1.z + c1.w) * 0.25f;
    d1.z = (-c1.x - c1.y + c1.z + c1.w) * 0.25f;
    d1.w = ( c1.x - c1.y - c1.z + c1.w) * 0.25f;

    const float* xl = xs + lane;
    float acc = 0.0f;

#pragma unroll 8
    for (int j = 0; j < 64; ++j) {
        const int   ix0 = __builtin_amdgcn_readlane(m0.x, j);
        const int   ix1 = __builtin_amdgcn_readlane(m0.y, j);
        const float A   = bcast_f(d0.x, j);
        const float Bc  = bcast_f(d0.y, j);
        const float Cc  = bcast_f(d0.z, j);
        const float Dd  = bcast_f(d0.w, j);
        const float x0  = xl[ix0 * STR];
        const float x1  = xl[ix1 * STR];
        acc += A;
        acc = fmaf(Bc, x0, acc);
        acc = fmaf(Cc, x1, acc);
        acc = fmaf(Dd, x0 * x1, acc);
    }
#pragma unroll 8
    for (int j = 0; j < 64; ++j) {
        const int   ix0 = __builtin_amdgcn_readlane(m1.x, j);
        const int   ix1 = __builtin_amdgcn_readlane(m1.y, j);
        const float A   = bcast_f(d1.x, j);
        const float Bc  = bcast_f(d1.y, j);
        const float Cc  = bcast_f(d1.z, j);
        const float Dd  = bcast_f(d1.w, j);
        const float x0  = xl[ix0 * STR];
        const float x1  = xl[ix1 * STR];
        acc += A;
        acc = fmaf(Bc, x0, acc);
        acc = fmaf(Cc, x1, acc);
        acc = fmaf(Dd, x0 * x1, acc);
    }

    red[w * B + lane] = acc;
    __syncthreads();

    // Waves 0,1 finish features 0,1: sum the 4 wave partials.
    if (w < 2) {
        const int oo = blockIdx.x * 2 + w;
        const int rb = w * 4 * B;
        const float s = red[rb + lane] + red[rb + B + lane] +
                        red[rb + 2 * B + lane] + red[rb + 3 * B + lane];
        out[lane * OUT + oo] = s + bias[oo];
    }
}

extern "C" void kernel_launch(void* const* d_in, const int* in_sizes, int n_in,
                              void* d_out, int out_size, void* d_ws, size_t ws_size,
                              hipStream_t stream) {
    const float*  input = (const float*)d_in[0];
    const int*    mask  = (const int*)d_in[1];
    const float*  lut   = (const float*)d_in[2];
    const float*  bias  = (const float*)d_in[3];
    float*        out   = (float*)d_out;

    dim3 grid(OUT / 2), block(512);
    lut_main_kernel<<<grid, block, 0, stream>>>(
        input, (const int2*)mask, (const float4*)lut, bias, out);
}

// Round 8
// 15.026 us; speedup vs baseline: 1.8994x; 1.2956x over previous
//
#include <hip/hip_runtime.h>

// Problem constants (fixed by reference setup_inputs):
//   B=64, IN=512, OUT=512, K=2, KK=4, T=IN*OUT=262144, TPO=T/OUT=512
constexpr int B    = 64;
constexpr int IN   = 512;
constexpr int OUT  = 512;
constexpr int T    = IN * OUT;
constexpr int TPO  = T / OUT;     // 512 tables per output feature
constexpr int STR  = 68;          // xs row stride (dwords): [IN][STR]
// Gather reads xs[i*68 + lane]: banks (4i+lane)%32 -> 2-way wave64 (free).
// Staging ds_write_b128 at xs[i*68 + b4]: lanes i..i+7 tile all 32 banks
// exactly once per phase (conflict-free).

__device__ __forceinline__ float bcast_f(float v, int j) {
    return __int_as_float(__builtin_amdgcn_readlane(__float_as_int(v), j));
}

// One block = 1024 threads = 16 waves = 4 waves/SIMD (1 block/CU, LDS-bound),
// 2 output features per block; grid = 256. lane = batch.
// Waves 0-7 -> feature 0 (64 tables each), waves 8-15 -> feature 1.
// Per wave: one int2 + one float4 coalesced load gives lane l table t0+l's
// mask/lut; bilinear transform (A,B,C,D) once per lane; A summed across the
// wave ONCE via shfl_xor; inner loop broadcasts lane j's regs via readlane
// (packed (i0|i1<<16) -> 4 readlanes/table) and gathers x0,x1 from LDS.
__global__ __launch_bounds__(1024, 1)
void lut_main_kernel(const float* __restrict__ input,   // [B][IN]
                     const int2*  __restrict__ mask2,   // [T]
                     const float4* __restrict__ lut,    // [T][4]
                     const float* __restrict__ bias,    // [OUT]
                     float* __restrict__ out) {         // [B][OUT]
    __shared__ float xs[IN * STR];    // 139.3 KB
    __shared__ float red[16 * B];     // 4 KB

    const int tid = threadIdx.x;

    // ---- Stage input as xs[i][b]; two threads share column i (halves). ----
    {
        const int i = tid & (IN - 1);
        const int h = tid >> 9;            // 0 or 1 -> batch halves
        for (int b4 = h * 32; b4 < h * 32 + 32; b4 += 4) {
            float a0 = input[(b4 + 0) * IN + i];
            float a1 = input[(b4 + 1) * IN + i];
            float a2 = input[(b4 + 2) * IN + i];
            float a3 = input[(b4 + 3) * IN + i];
            *reinterpret_cast<float4*>(&xs[i * STR + b4]) =
                make_float4(a0, a1, a2, a3);
        }
    }
    __syncthreads();

    const int lane = tid & 63;            // batch
    const int w    = tid >> 6;            // wave 0..15
    const int o    = blockIdx.x * 2 + (w >> 3);
    const int t0   = o * TPO + (w & 7) * 64;

    // One table per lane: 2 coalesced VMEM loads cover the wave's 64 tables.
    const int2   m = mask2[t0 + lane];
    const float4 c = lut[t0 + lane];
    const float A  = ( c.x + c.y + c.z + c.w) * 0.25f;
    const float Bc = (-c.x + c.y - c.z + c.w) * 0.25f;
    const float Cc = (-c.x - c.y + c.z + c.w) * 0.25f;
    const float Dd = ( c.x - c.y - c.z + c.w) * 0.25f;
    const int   pk = (m.x & 0xFFFF) | (m.y << 16);   // i0 | i1<<16 (both <512)

    // Sum of A over the wave's 64 tables -- same for every batch lane.
    float sA = A;
#pragma unroll
    for (int s = 32; s; s >>= 1) sA += __shfl_xor(sA, s);

    const float* xl = xs + lane;
    float acc0 = 0.0f, acc1 = 0.0f;

#pragma unroll 8
    for (int j = 0; j < 64; j += 2) {
        {
            const int   p  = __builtin_amdgcn_readlane(pk, j);
            const float Bb = bcast_f(Bc, j);
            const float CC = bcast_f(Cc, j);
            const float DD = bcast_f(Dd, j);
            const float x0 = xl[(p & 0xFFFF) * STR];
            const float x1 = xl[(p >> 16) * STR];
            acc0 = fmaf(Bb, x0, acc0);
            acc0 = fmaf(CC, x1, acc0);
            acc0 = fmaf(DD, x0 * x1, acc0);
        }
        {
            const int   p  = __builtin_amdgcn_readlane(pk, j + 1);
            const float Bb = bcast_f(Bc, j + 1);
            const float CC = bcast_f(Cc, j + 1);
            const float DD = bcast_f(Dd, j + 1);
            const float x0 = xl[(p & 0xFFFF) * STR];
            const float x1 = xl[(p >> 16) * STR];
            acc1 = fmaf(Bb, x0, acc1);
            acc1 = fmaf(CC, x1, acc1);
            acc1 = fmaf(DD, x0 * x1, acc1);
        }
    }

    red[w * B + lane] = acc0 + acc1 + sA;
    __syncthreads();

    // Waves 0,1 finish features 0,1: sum the 8 wave partials each.
    if (tid < 2 * B) {
        const int f  = tid >> 6;
        const int b  = tid & 63;
        const int rb = f * 8 * B;
        float s = 0.0f;
#pragma unroll
        for (int q = 0; q < 8; ++q) s += red[rb + q * B + b];
        const int oo = blockIdx.x * 2 + f;
        out[b * OUT + oo] = s + bias[oo];
    }
}

extern "C" void kernel_launch(void* const* d_in, const int* in_sizes, int n_in,
                              void* d_out, int out_size, void* d_ws, size_t ws_size,
                              hipStream_t stream) {
    const float*  input = (const float*)d_in[0];
    const int*    mask  = (const int*)d_in[1];
    const float*  lut   = (const float*)d_in[2];
    const float*  bias  = (const float*)d_in[3];
    float*        out   = (float*)d_out;

    dim3 grid(OUT / 2), block(1024);
    lut_main_kernel<<<grid, block, 0, stream>>>(
        input, (const int2*)mask, (const float4*)lut, bias, out);
}

// Round 9
// 12.289 us; speedup vs baseline: 2.3225x; 1.2228x over previous
//
#include <hip/hip_runtime.h>

// Problem constants (fixed by reference setup_inputs):
//   B=64, IN=512, OUT=512, K=2, KK=4, T=IN*OUT=262144, TPO=T/OUT=512
constexpr int B    = 64;
constexpr int IN   = 512;
constexpr int OUT  = 512;
constexpr int T    = IN * OUT;
constexpr int TPO  = T / OUT;     // 512 tables per output feature
constexpr int STR  = 68;          // xs row stride (dwords): [IN][STR]
// Gather ds_read_b128 at xs[i*68 + 4*bq] (bq=0..15): byte addr 272*i+16*bq,
// 16B-aligned; within an 8-lane phase the 16B blocks tile all 32 banks
// exactly once (start banks 4(i+bq)%32) -> conflict-free.
// Staging ds_write_b128 at xs[i*68 + b4]: same tiling, conflict-free.

// One block = 1024 threads = 16 waves = 4 waves/SIMD (1 block/CU, LDS 143 KB),
// 2 output features per block; grid = 256.
// Lane split: tg = lane>>4 (table subgroup 0..3), bq = lane&15 (batch quad).
// Wave w owns 64 tables; per step s it processes 4 tables (t0+4s+tg), each
// lane gathering float4(batches 4bq..4bq+3) for x0,x1 via ds_read_b128 --
// 2 LDS instrs per 4 tables (vs 2 per table before). Table mask/lut come
// from in-loop VMEM loads at constant immediate offsets (4 distinct addrs
// per wave, lane-replicated -> one L1 transaction; off the LDS pipe).
__global__ __launch_bounds__(1024, 4)
void lut_main_kernel(const float* __restrict__ input,   // [B][IN]
                     const int2*  __restrict__ mask2,   // [T]
                     const float4* __restrict__ lut,    // [T][4]
                     const float* __restrict__ bias,    // [OUT]
                     float* __restrict__ out) {         // [B][OUT]
    __shared__ float  xs[IN * STR];     // 139.3 KB
    __shared__ float4 red4[16 * 16];    // 4 KB: [wave][bq]

    const int tid = threadIdx.x;

    // ---- Stage input as xs[i][b]; two threads share column i (halves). ----
    {
        const int i = tid & (IN - 1);
        const int h = tid >> 9;            // 0 or 1 -> batch halves
        for (int b4 = h * 32; b4 < h * 32 + 32; b4 += 4) {
            float a0 = input[(b4 + 0) * IN + i];
            float a1 = input[(b4 + 1) * IN + i];
            float a2 = input[(b4 + 2) * IN + i];
            float a3 = input[(b4 + 3) * IN + i];
            *reinterpret_cast<float4*>(&xs[i * STR + b4]) =
                make_float4(a0, a1, a2, a3);
        }
    }
    __syncthreads();

    const int lane = tid & 63;
    const int w    = tid >> 6;            // wave 0..15
    const int o    = blockIdx.x * 2 + (w >> 3);
    const int t0   = o * TPO + (w & 7) * 64;

    // Prologue: sum of A over the wave's 64 tables (also warms L1 for lut).
    const float4 cA = lut[t0 + lane];
    float sA = (cA.x + cA.y + cA.z + cA.w) * 0.25f;
#pragma unroll
    for (int s = 32; s; s >>= 1) sA += __shfl_xor(sA, s);

    const int bq = lane & 15;             // batch quad: batches 4bq..4bq+3
    const int tg = lane >> 4;             // table subgroup 0..3
    const float* xq = xs + 4 * bq;

    const int2*   mp = mask2 + t0 + tg;
    const float4* lp = lut   + t0 + tg;

    float4 acc = make_float4(0.f, 0.f, 0.f, 0.f);

#pragma unroll 4
    for (int s = 0; s < 16; ++s) {
        const int2   m = mp[4 * s];       // const imm offset VMEM
        const float4 c = lp[4 * s];
        const float Bc = (-c.x + c.y - c.z + c.w) * 0.25f;
        const float Cc = (-c.x - c.y + c.z + c.w) * 0.25f;
        const float Dd = ( c.x - c.y - c.z + c.w) * 0.25f;
        const float4 x0 = *reinterpret_cast<const float4*>(xq + m.x * STR);
        const float4 x1 = *reinterpret_cast<const float4*>(xq + m.y * STR);
        acc.x = fmaf(Bc, x0.x, fmaf(Cc, x1.x, fmaf(Dd, x0.x * x1.x, acc.x)));
        acc.y = fmaf(Bc, x0.y, fmaf(Cc, x1.y, fmaf(Dd, x0.y * x1.y, acc.y)));
        acc.z = fmaf(Bc, x0.z, fmaf(Cc, x1.z, fmaf(Dd, x0.z * x1.z, acc.z)));
        acc.w = fmaf(Bc, x0.w, fmaf(Cc, x1.w, fmaf(Dd, x0.w * x1.w, acc.w)));
    }

    // Reduce over the 4 tg subgroups (lanes l, l^16, l^32, l^48).
    acc.x += __shfl_xor(acc.x, 16);  acc.y += __shfl_xor(acc.y, 16);
    acc.z += __shfl_xor(acc.z, 16);  acc.w += __shfl_xor(acc.w, 16);
    acc.x += __shfl_xor(acc.x, 32);  acc.y += __shfl_xor(acc.y, 32);
    acc.z += __shfl_xor(acc.z, 32);  acc.w += __shfl_xor(acc.w, 32);

    if (lane < 16)
        red4[w * 16 + bq] = make_float4(acc.x + sA, acc.y + sA,
                                        acc.z + sA, acc.w + sA);
    __syncthreads();

    // Cross-wave: feature f sums its 8 wave partials. 128 threads cover
    // 2 features x 64 batches (bq = si>>2, component c = si&3).
    if (tid < 128) {
        const int f  = tid >> 6;
        const int si = tid & 63;
        const int q2 = si >> 2;
        const int c  = si & 3;
        const float* rs = reinterpret_cast<const float*>(red4);
        float s = 0.f;
#pragma unroll
        for (int q = 0; q < 8; ++q)
            s += rs[((8 * f + q) * 16 + q2) * 4 + c];
        const int oo = blockIdx.x * 2 + f;
        out[(4 * q2 + c) * OUT + oo] = s + bias[oo];
    }
}

extern "C" void kernel_launch(void* const* d_in, const int* in_sizes, int n_in,
                              void* d_out, int out_size, void* d_ws, size_t ws_size,
                              hipStream_t stream) {
    const float*  input = (const float*)d_in[0];
    const int*    mask  = (const int*)d_in[1];
    const float*  lut   = (const float*)d_in[2];
    const float*  bias  = (const float*)d_in[3];
    float*        out   = (float*)d_out;

    dim3 grid(OUT / 2), block(1024);
    lut_main_kernel<<<grid, block, 0, stream>>>(
        input, (const int2*)mask, (const float4*)lut, bias, out);
}